// Round 11
// baseline (404.016 us; speedup 1.0000x reference)
//
#include <hip/hip_runtime.h>
#include <math.h>

// AFNO block, MI355X. Spectral path: bf16 MFMA DFT stages vs constant twiddle
// tables. MLP: bf16 MFMA GEMMs with 3-deep counted-vmcnt pipeline (T3/T4:
// raw s_barrier, loads in flight across barriers). LN2 folded into GEMM1
// epilogue (standalone stats kernel). Residual+bias fused into GEMM2.

#define BB 8
#define CC 384
#define WF 33
#define NBK 8
#define BSZ 48
#define NTOK 32768
#define TW64 0.09817477042468103f  // 2*pi/64

#define T_AWF 0
#define T_AHF 5120
#define T_AHI 21504
#define T_AWI 37888

typedef __attribute__((ext_vector_type(8))) short bf16x8;
typedef __attribute__((ext_vector_type(4))) float f32x4;

__device__ __forceinline__ unsigned short f2b(float f) {
  union { float f; unsigned u; } x; x.f = f;
  unsigned u = x.u;
  return (unsigned short)((u + 0x7fffu + ((u >> 16) & 1u)) >> 16);
}
__device__ __forceinline__ float b2fl(unsigned short u) {
  return __uint_as_float(((unsigned)u) << 16);
}
__device__ __forceinline__ void gload16(const void* g, void* l) {
  __builtin_amdgcn_global_load_lds(
      (const __attribute__((address_space(1))) void*)g,
      (__attribute__((address_space(3))) void*)l, 16, 0, 0);
}

// ---------------- prep: twiddles + weight transposes + LN2 fold vectors --------
__global__ __launch_bounds__(256) void prep_kernel(unsigned short* __restrict__ A,
    const float* __restrict__ mw1, unsigned short* __restrict__ w1t,
    const float* __restrict__ mw2, unsigned short* __restrict__ w2t,
    const float* __restrict__ n2w, const float* __restrict__ n2b,
    const float* __restrict__ mb1, float2* __restrict__ gsbb) {
  __shared__ float tile[32][33];
  int bid = blockIdx.x;
  if (bid < 64) {
    int idx0 = bid * 256 + threadIdx.x;
    const float S = 0.125f;
    for (int e = idx0; e < 5120; e += 16384) {
      int m = e >> 6, w = e & 63;
      float val = 0.f;
      if (m < 66) {
        int kwv = m >> 1;
        float th = (float)((kwv * w) & 63) * TW64;
        val = (m & 1) ? (((kwv==0)||(kwv==32)) ? 0.f : -sinf(th)*S) : cosf(th)*S;
      }
      A[T_AWF + e] = f2b(val);
    }
    for (int e = idx0; e < 16384; e += 16384) {
      int comp = e >> 13; int r = e & 8191; int mp = r >> 6, hh = r & 63;
      int cpo = mp >> 6, kh = mp & 63;
      float th = (float)((kh * hh) & 63) * TW64;
      float cv = cosf(th), sv = sinf(th);
      float fv = (cpo == 0) ? (comp == 0 ? cv : sv) : (comp == 0 ? -sv : cv);
      A[T_AHF + e] = f2b(fv * S);
      float iv = (cpo == 0) ? (comp == 0 ? cv : -sv) : (comp == 0 ? sv : cv);
      A[T_AHI + e] = f2b(iv * S);
    }
    for (int e = idx0; e < 4096; e += 16384) {
      int w = e >> 6, kp = e & 63;
      float val;
      if (kp <= 32) {
        float th = (float)((kp * w) & 63) * TW64;
        val = cosf(th) * (((kp==0)||(kp==32)) ? 1.f : 2.f) * S;
      } else {
        int k2 = kp - 32;
        float th = (float)((k2 * w) & 63) * TW64;
        val = -2.f * sinf(th) * S;
      }
      A[T_AWI + e] = f2b(val);
    }
    return;
  }
  if (bid >= 1216) {
    int n0 = (bid - 1216) * 256 + threadIdx.x;
    if (n0 < 1536) {
      float gsv = 0.f, bbv = 0.f;
      for (int k = 0; k < 384; ++k) {
        float a = mw1[(size_t)k*1536 + n0];
        gsv += n2w[k]*a;
        bbv += n2b[k]*a;
      }
      gsbb[n0] = make_float2(gsv, bbv + mb1[n0]);
    }
    return;
  }
  int tx = threadIdx.x & 31, ty = threadIdx.x >> 5;
  if (bid < 640) {
    int tb = bid - 64;
    int ntc = 1536 >> 5;
    int bx = tb % ntc, by = tb / ntc;
    for (int rr2 = ty; rr2 < 32; rr2 += 8)
      tile[rr2][tx] = mw1[(size_t)(by*32+rr2)*1536 + bx*32 + tx];
    __syncthreads();
    float gv = n2w[by*32 + tx];
    for (int rr2 = ty; rr2 < 32; rr2 += 8)
      w1t[(size_t)(bx*32+rr2)*384 + by*32 + tx] = f2b(tile[tx][rr2] * gv);
  } else {
    int tb = bid - 640;
    int ntc = 384 >> 5;
    int bx = tb % ntc, by = tb / ntc;
    for (int rr2 = ty; rr2 < 32; rr2 += 8)
      tile[rr2][tx] = mw2[(size_t)(by*32+rr2)*384 + bx*32 + tx];
    __syncthreads();
    for (int rr2 = ty; rr2 < 32; rr2 += 8)
      w2t[(size_t)(bx*32+rr2)*1536 + by*32 + tx] = f2b(tile[tx][rr2]);
  }
}

// ---------------- LN1 fused with transpose: x[b,h,w,c] -> xn[b,h,c,w] bf16 -----
__global__ __launch_bounds__(256) void ln1t_kernel(const float* __restrict__ x,
    const float* __restrict__ g, const float* __restrict__ be,
    unsigned short* __restrict__ xn) {
  int outer = blockIdx.x;  // b*64+h
  int tid = threadIdx.x, lane = tid & 63, wg = tid >> 6;
  const float* base = x + (size_t)outer * 64 * 384;
  float s[16], s2[16];
#pragma unroll
  for (int q = 0; q < 16; ++q) { s[q] = 0.f; s2[q] = 0.f; }
  for (int ch = 0; ch < 6; ++ch) {
#pragma unroll
    for (int q = 0; q < 16; ++q) {
      float v = base[(size_t)(wg*16 + q)*384 + ch*64 + lane];
      s[q] += v; s2[q] += v*v;
    }
  }
#pragma unroll
  for (int q = 0; q < 16; ++q) {
#pragma unroll
    for (int off = 32; off >= 1; off >>= 1) {
      s[q] += __shfl_xor(s[q], off);
      s2[q] += __shfl_xor(s2[q], off);
    }
  }
  float mu[16], rs[16];
#pragma unroll
  for (int q = 0; q < 16; ++q) {
    mu[q] = s[q] * (1.f/384.f);
    rs[q] = rsqrtf(s2[q] * (1.f/384.f) - mu[q]*mu[q] + 1e-5f);
  }
  unsigned short* o = xn + (size_t)outer * 384 * 64;
  for (int ch = 0; ch < 6; ++ch) {
    int c = ch*64 + lane;
    float ga = g[c], bb2 = be[c];
#pragma unroll
    for (int qq = 0; qq < 4; ++qq) {
      unsigned short hv[4];
#pragma unroll
      for (int r2 = 0; r2 < 4; ++r2) {
        int q = qq*4 + r2;
        hv[r2] = f2b((base[(size_t)(wg*16+q)*384 + c]-mu[q])*rs[q]*ga + bb2);
      }
      uint2 pw;
      pw.x = hv[0] | ((unsigned)hv[1] << 16);
      pw.y = hv[2] | ((unsigned)hv[3] << 16);
      *(uint2*)(o + (size_t)c*64 + wg*16 + qq*4) = pw;
    }
  }
}

// ---------------- DFT stage as MFMA GEMM (single bf16 plane) -------------------
// STAGE: 0=W-fwd, 1=H-fwd, 2=H-inv, 3=W-inv
template<int STAGE>
__global__ __launch_bounds__(256) void dft_kernel(
    const unsigned short* __restrict__ A0, const unsigned short* __restrict__ D,
    unsigned short* __restrict__ O) {
  constexpr int M = (STAGE==0) ? 80 : (STAGE==3) ? 64 : 128;
  constexpr int MT = M / 16;
  constexpr int NA = (STAGE==1 || STAGE==2) ? 2 : 1;
  constexpr int ABYTES = NA * M * 128;
  constexpr int STG2 = ABYTES + 16384;
  constexpr int EPB = 64 * 128 * 4;
  constexpr int SB = (STG2 > EPB) ? STG2 : EPB;
  __shared__ __align__(16) char smem[SB];
  char* BPL = smem + ABYTES;

  int bid = blockIdx.x;
  int cc = bid % 3; int outer = bid / 3;
  int c0 = cc * 128;
  int tid = threadIdx.x, lane = tid & 63, wid = tid >> 6;
  int rr = lane & 15, rq = lane >> 4;
  int b, h = 0, kw = 0;
  if (STAGE == 0 || STAGE == 3) { b = outer >> 6; h = outer & 63; }
  else { b = outer / 33; kw = outer % 33; }

  f32x4 acc[MT][2];
#pragma unroll
  for (int mt = 0; mt < MT; ++mt)
#pragma unroll
    for (int nt = 0; nt < 2; ++nt) acc[mt][nt] = (f32x4){0.f,0.f,0.f,0.f};

  const unsigned short* Atab =
    (STAGE==0) ? A0+T_AWF : (STAGE==1) ? A0+T_AHF : (STAGE==2) ? A0+T_AHI : A0+T_AWI;
  constexpr int ACH = NA * M * 8;
#pragma unroll
  for (int i = 0; i < (ACH + 255)/256; ++i) {
    int t2 = tid + i*256;
    if ((ACH % 256 == 0) || (t2 < ACH)) {
      int mm = t2 >> 3, ch = t2 & 7;
      gload16(Atab + mm*64 + ((ch ^ (mm & 7)) << 3), smem + i*4096 + wid*1024);
    }
  }

  int ncomp = (STAGE == 1) ? ((kw == 0 || kw == 32) ? 1 : 2) : NA;

  for (int comp = 0; comp < ncomp; ++comp) {
    if (comp) __syncthreads();
    if (STAGE == 0) {
      const unsigned short* src = D + (((size_t)(b*64 + h))*384 + c0) * 64;
#pragma unroll
      for (int i = 0; i < 4; ++i) {
        int idx = tid + i*256;
        int c = idx >> 3, ch = idx & 7;
        gload16(src + c*64 + ((ch ^ (c & 7)) << 3), BPL + i*4096 + wid*1024);
      }
    } else {
      size_t P; int RS;
      if (STAGE == 1) { P = (size_t)b*(64*66*384) + (size_t)(2*kw + comp)*384 + c0; RS = 66*384; }
      else if (STAGE == 2) { P = ((size_t)((b*2 + comp)*33) + kw)*64*384 + c0; RS = 384; }
      else { P = (size_t)b*(64*64*384) + (size_t)h*384 + c0; RS = 64*384; }
      const unsigned short* p0 = D + P;
#pragma unroll
      for (int i = 0; i < 4; ++i) {
        int kq = (tid >> 6) + i*4;
        int c2 = (tid & 63) * 2;
        const unsigned short* p = p0 + (size_t)(4*kq)*RS + c2;
        unsigned u0 = *(const unsigned*)p;
        unsigned u1 = *(const unsigned*)(p + RS);
        unsigned u2 = *(const unsigned*)(p + 2*(size_t)RS);
        unsigned u3 = *(const unsigned*)(p + 3*(size_t)RS);
        uint2 w0, w1v;
        w0.x = (u0 & 0xffffu) | (u1 << 16);
        w0.y = (u2 & 0xffffu) | (u3 << 16);
        w1v.x = (u0 >> 16) | (u1 & 0xffff0000u);
        w1v.y = (u2 >> 16) | (u3 & 0xffff0000u);
        *(uint2*)(BPL + c2*128 + ((kq*8) ^ ((c2 & 7) << 4))) = w0;
        *(uint2*)(BPL + (c2+1)*128 + ((kq*8) ^ (((c2+1) & 7) << 4))) = w1v;
      }
    }
    __syncthreads();
#pragma unroll
    for (int kh2 = 0; kh2 < 2; ++kh2) {
      int chb = kh2*4 + rq;
      bf16x8 bfr[2];
#pragma unroll
      for (int nt = 0; nt < 2; ++nt) {
        int n = wid*32 + nt*16 + rr;
        bfr[nt] = *(const bf16x8*)(BPL + n*128 + ((chb ^ (n & 7)) << 4));
      }
#pragma unroll
      for (int mt = 0; mt < MT; ++mt) {
        int mr = mt*16 + rr;
        bf16x8 af = *(const bf16x8*)(smem + comp*(M*128) + mr*128 + ((chb ^ (mr & 7)) << 4));
#pragma unroll
        for (int nt = 0; nt < 2; ++nt)
          acc[mt][nt] = __builtin_amdgcn_mfma_f32_16x16x32_bf16(af, bfr[nt], acc[mt][nt], 0, 0, 0);
      }
    }
  }
  __syncthreads();

  float* ep = (float*)smem;
  constexpr int NHM = (M + 63) / 64;
#pragma unroll
  for (int hm = 0; hm < NHM; ++hm) {
    if (hm) __syncthreads();
#pragma unroll
    for (int mo = 0; mo < 4; ++mo) {
      int mt = hm*4 + mo;
      if (mt >= MT) break;
#pragma unroll
      for (int nt = 0; nt < 2; ++nt)
#pragma unroll
        for (int j = 0; j < 4; ++j) {
          int m2 = mo*16 + rq*4 + j;
          int cl = wid*32 + nt*16 + rr;
          ep[m2*128 + (cl ^ ((m2 & 7) << 2))] = acc[mt][nt][j];
        }
    }
    __syncthreads();
    for (int it = tid; it < 64*16; it += 256) {
      int m2 = it >> 4, u8 = it & 15;
      int m = hm*64 + m2;
      if (m >= M) break;
      if (STAGE == 0 && m >= 66) break;
      if (STAGE == 2) { int cp = m >> 6; if (cp && (kw == 0 || kw == 32)) continue; }
      int swz = (m2 & 7) << 2;
      float4 v0 = *(const float4*)(ep + m2*128 + ((u8*8) ^ swz));
      float4 v1 = *(const float4*)(ep + m2*128 + ((u8*8 + 4) ^ swz));
      uint4 pw;
      pw.x = f2b(v0.x) | ((unsigned)f2b(v0.y) << 16);
      pw.y = f2b(v0.z) | ((unsigned)f2b(v0.w) << 16);
      pw.z = f2b(v1.x) | ((unsigned)f2b(v1.y) << 16);
      pw.w = f2b(v1.z) | ((unsigned)f2b(v1.w) << 16);
      size_t rowb;
      if (STAGE == 0) rowb = ((size_t)(b*64 + h)*66 + m)*384 + c0;
      else if (STAGE == 1) { int cp = m >> 6, kh = m & 63;
        rowb = (((size_t)((b*2 + cp)*64 + kh)*33) + kw)*384 + c0; }
      else if (STAGE == 2) { int cp = m >> 6, h2 = m & 63; int kp = cp ? 32 + kw : kw;
        rowb = ((size_t)(b*64 + kp)*64 + h2)*384 + c0; }
      else rowb = ((size_t)(b*64 + h)*64 + m)*384 + c0;
      *(uint4*)(O + rowb + u8*8) = pw;
    }
  }
}

// ---------------- block-diag complex matmul + ReLU: 2 modes/block --------------
__global__ __launch_bounds__(384) void blockmm2_kernel(
    const unsigned short* __restrict__ S2, const float* __restrict__ w1,
    const float* __restrict__ b1, unsigned short* __restrict__ o1) {
  int bid = blockIdx.x;
  int np = bid % 4;
  int kw = (bid / 4) % WF;
  int h = bid / (4*WF);
  int tid = threadIdx.x;
  __shared__ float4 wl4[2][48*24];
  __shared__ float2 xl[2][BB][48];
  __shared__ float2 bl[2][48];
#pragma unroll
  for (int e = tid; e < 2304; e += 384) {
    int sub = e / 1152, r = e % 1152;
    const float4* wb4 = (const float4*)(w1 + ((size_t)((h*WF + kw)*NBK) + 2*np + sub)*(BSZ*BSZ*2));
    wl4[sub][r] = wb4[r];
  }
  if (tid < 96) {
    int sub = tid / 48, o = tid % 48;
    bl[sub][o] = ((const float2*)b1)[((size_t)((h*WF + kw)*NBK) + 2*np + sub)*BSZ + o];
  }
#pragma unroll
  for (int e = tid; e < 768; e += 384) {
    int sub = e / 384, r = e % 384, bb = r / 48, i = r % 48;
    int n = 2*np + sub;
    size_t ir = (((size_t)((bb*2 + 0)*64 + h)*33) + kw)*384 + n*48 + i;
    size_t ii = (((size_t)((bb*2 + 1)*64 + h)*33) + kw)*384 + n*48 + i;
    xl[sub][bb][i] = make_float2(b2fl(S2[ir]), b2fl(S2[ii]));
  }
  __syncthreads();
  int sub = tid / 192, r = tid % 192, bb = r / 24, o2 = r % 24;
  float4 bv = *(const float4*)(&bl[sub][2*o2]);
  float2 a0 = make_float2(bv.x, bv.y);
  float2 a1 = make_float2(bv.z, bv.w);
#pragma unroll
  for (int i = 0; i < 48; ++i) {
    float2 xv = xl[sub][bb][i];
    float4 wv = wl4[sub][i*24 + o2];
    a0.x += xv.x*wv.x - xv.y*wv.y;
    a0.y += xv.x*wv.y + xv.y*wv.x;
    a1.x += xv.x*wv.z - xv.y*wv.w;
    a1.y += xv.x*wv.w + xv.y*wv.z;
  }
  int n = 2*np + sub;
  size_t idr = (((size_t)((bb*2 + 0)*33) + kw)*64 + h)*384 + n*48 + 2*o2;
  size_t idi = (((size_t)((bb*2 + 1)*33) + kw)*64 + h)*384 + n*48 + 2*o2;
  *(unsigned*)(o1 + idr) = f2b(fmaxf(a0.x, 0.f)) | ((unsigned)f2b(fmaxf(a1.x, 0.f)) << 16);
  *(unsigned*)(o1 + idi) = f2b(fmaxf(a0.y, 0.f)) | ((unsigned)f2b(fmaxf(a1.y, 0.f)) << 16);
}

// ---------------- LN2 stats: per-token (mu, rs) from xsb ------------------------
__global__ __launch_bounds__(256) void stats_kernel(const unsigned short* __restrict__ in,
    float2* __restrict__ stats) {
  int token = blockIdx.x * 4 + (threadIdx.x >> 6);
  int lane = threadIdx.x & 63;
  const unsigned short* row = in + (size_t)token * CC;
  float s = 0.f, s2 = 0.f;
#pragma unroll
  for (int j = 0; j < 6; ++j) {
    float v = b2fl(row[lane + 64*j]);
    s += v; s2 += v*v;
  }
#pragma unroll
  for (int off = 32; off >= 1; off >>= 1) {
    s += __shfl_xor(s, off);
    s2 += __shfl_xor(s2, off);
  }
  if (lane == 0) {
    float mu = s * (1.0f/CC);
    float rs = rsqrtf(s2 * (1.0f/CC) - mu*mu + 1e-5f);
    stats[token] = make_float2(mu, rs);
  }
}

// ---------------- bf16 MFMA GEMM, BK=32, 3-deep counted-vmcnt pipeline ---------
// MODE 0: v = rs*acc - rs*mu*gs[n] + bb[n]; gelu; bf16 store (GEMM1, LN2 folded)
// MODE 1: out = acc + xs(bf16) + x + b2, fp32 (GEMM2, residual fused)
template<int MODE>
__global__ __launch_bounds__(256) void mfma_gemm_kernel(
    const unsigned short* __restrict__ A, int lda,
    const unsigned short* __restrict__ BT, int ldbt,
    void* __restrict__ Cp, int ldc, int K, int ntn,
    const float2* __restrict__ stats, const float2* __restrict__ gsbb,
    const unsigned short* __restrict__ xsb, const float* __restrict__ xres,
    const float* __restrict__ b2v) {
  __shared__ __align__(16) char gsm[49152];  // 3 bufs x (A 8KB + B 8KB)
  int nb = (int)gridDim.x;
  int bidx = (int)blockIdx.x;
  int bswz = (bidx & 7) * (nb >> 3) + (bidx >> 3);
  int bn = bswz % ntn;
  int bm = bswz / ntn;
  int t = threadIdx.x;
  int lane = t & 63;
  int wid = t >> 6;
  int wm = wid >> 1, wn = wid & 1;
  int rr = lane & 15, rq = lane >> 4;

  f32x4 acc[4][4];
#pragma unroll
  for (int m = 0; m < 4; ++m)
#pragma unroll
    for (int n = 0; n < 4; ++n) acc[m][n] = (f32x4){0.f,0.f,0.f,0.f};

  const unsigned short* Abase = A + (size_t)bm*128*lda;
  const unsigned short* Bbase = BT + (size_t)bn*128*ldbt;
  int nt = K >> 5;

  // 4 vmcnt-counted loads per STG (2 A + 2 B per thread)
#define STG(bsel, t0)                                                        \
  {                                                                          \
    _Pragma("unroll")                                                        \
    for (int i = 0; i < 2; ++i) {                                            \
      int u = t + i*256;                                                     \
      int row = u >> 2, ch = u & 3;                                          \
      gload16(Abase + (size_t)row*lda + (t0)*32 + ((ch ^ (row & 3)) << 3),   \
              gsm + (bsel)*16384 + i*4096 + wid*1024);                       \
      gload16(Bbase + (size_t)row*ldbt + (t0)*32 + ((ch ^ (row & 3)) << 3),  \
              gsm + (bsel)*16384 + 8192 + i*4096 + wid*1024);                \
    }                                                                        \
  }

#define CMP(bsel)                                                            \
  {                                                                          \
    const char* Ab2 = gsm + (bsel)*16384;                                    \
    const char* Bb2 = Ab2 + 8192;                                            \
    bf16x8 af[4], bfv[4];                                                    \
    _Pragma("unroll")                                                        \
    for (int m = 0; m < 4; ++m) {                                            \
      int row = wm*64 + m*16 + rr;                                           \
      af[m] = *(const bf16x8*)(Ab2 + row*64 + ((rq ^ (row & 3)) << 4));      \
    }                                                                        \
    _Pragma("unroll")                                                        \
    for (int n = 0; n < 4; ++n) {                                            \
      int row = wn*64 + n*16 + rr;                                           \
      bfv[n] = *(const bf16x8*)(Bb2 + row*64 + ((rq ^ (row & 3)) << 4));     \
    }                                                                        \
    _Pragma("unroll")                                                        \
    for (int m = 0; m < 4; ++m)                                              \
      _Pragma("unroll")                                                      \
      for (int n = 0; n < 4; ++n)                                            \
        acc[m][n] = __builtin_amdgcn_mfma_f32_16x16x32_bf16(af[m], bfv[n], acc[m][n], 0, 0, 0); \
  }

  // prologue: 2 tiles in flight
  STG(0, 0);
  STG(1, 1);
  int cur = 0;
  for (int tt = 0; tt < nt; ++tt) {
    if (tt + 2 < nt) {
      int nb3 = cur + 2; if (nb3 >= 3) nb3 -= 3;
      STG(nb3, tt + 2);
      __builtin_amdgcn_sched_barrier(0);
      asm volatile("s_waitcnt vmcnt(8)" ::: "memory");
    } else if (tt + 1 < nt) {
      __builtin_amdgcn_sched_barrier(0);
      asm volatile("s_waitcnt vmcnt(4)" ::: "memory");
    } else {
      __builtin_amdgcn_sched_barrier(0);
      asm volatile("s_waitcnt vmcnt(0)" ::: "memory");
    }
    __builtin_amdgcn_sched_barrier(0);
    __builtin_amdgcn_s_barrier();     // all waves: buffer cur ready
    __builtin_amdgcn_sched_barrier(0);
    CMP(cur);
    __builtin_amdgcn_s_barrier();     // all waves done reading cur before restage
    cur = (cur + 1 == 3) ? 0 : cur + 1;
  }
  __syncthreads();
#undef STG
#undef CMP

  if (MODE == 0) {
    // LN2-affine + GELU, bf16 store via LDS repack
    unsigned short* ep = (unsigned short*)gsm;
#pragma unroll
    for (int m = 0; m < 4; ++m) {
      float2 st[4];
#pragma unroll
      for (int j = 0; j < 4; ++j)
        st[j] = stats[bm*128 + wm*64 + m*16 + rq*4 + j];
#pragma unroll
      for (int n = 0; n < 4; ++n) {
        int lcol = wn*64 + n*16 + rr;
        float2 gb = gsbb[bn*128 + lcol];
#pragma unroll
        for (int j = 0; j < 4; ++j) {
          float v = st[j].y * acc[m][n][j] - st[j].y * st[j].x * gb.x + gb.y;
          v = 0.5f*v*(1.f + erff(v*0.70710678118654752f));
          int row = wm*64 + m*16 + rq*4 + j;
          ep[row*128 + (lcol ^ ((row & 7) << 3))] = f2b(v);
        }
      }
    }
    __syncthreads();
    for (int it = t; it < 128*16; it += 256) {
      int m = it >> 4, u8 = it & 15;
      uint4 pw = *(const uint4*)(ep + m*128 + ((u8*8) ^ ((m & 7) << 3)));
      *(uint4*)((unsigned short*)Cp + (size_t)(bm*128 + m)*ldc + bn*128 + u8*8) = pw;
    }
  } else {
    // out = acc + xs(bf16) + x + b2, fp32, via 2-half LDS repack
    float* ep = (float*)gsm;
#pragma unroll
    for (int half = 0; half < 2; ++half) {
      __syncthreads();
#pragma unroll
      for (int mo = 0; mo < 2; ++mo) {
        int m = half*2 + mo;
#pragma unroll
        for (int n = 0; n < 4; ++n)
#pragma unroll
          for (int j = 0; j < 4; ++j) {
            int lr = wm*32 + mo*16 + rq*4 + j;
            int col = wn*64 + n*16 + rr;
            ep[lr*128 + (col ^ ((lr & 7) << 2))] = acc[m][n][j];
          }
      }
      __syncthreads();
      for (int it = t; it < 64*32; it += 256) {
        int lr = it >> 5, u = it & 31;
        int swz = (lr & 7) << 2;
        float4 v = *(const float4*)(ep + lr*128 + ((u*4) ^ swz));
        int grow = bm*128 + (lr >> 5)*64 + (half*2 + ((lr >> 4) & 1))*16 + (lr & 15);
        int gcol = bn*128 + u*4;
        size_t idx = (size_t)grow*ldc + gcol;
        float4 xr = *(const float4*)(xres + idx);
        uint2 xsv = *(const uint2*)(xsb + idx);
        float4 bv = *(const float4*)(b2v + gcol);
        float4 ov;
        ov.x = v.x + xr.x + b2fl((unsigned short)(xsv.x & 0xffffu)) + bv.x;
        ov.y = v.y + xr.y + b2fl((unsigned short)(xsv.x >> 16)) + bv.y;
        ov.z = v.z + xr.z + b2fl((unsigned short)(xsv.y & 0xffffu)) + bv.z;
        ov.w = v.w + xr.w + b2fl((unsigned short)(xsv.y >> 16)) + bv.w;
        *(float4*)((float*)Cp + idx) = ov;
      }
    }
  }
}

extern "C" void kernel_launch(void* const* d_in, const int* in_sizes, int n_in,
                              void* d_out, int out_size, void* d_ws, size_t ws_size,
                              hipStream_t stream) {
  const float* x   = (const float*)d_in[0];
  const float* w1  = (const float*)d_in[1];
  const float* b1  = (const float*)d_in[2];
  const float* n1w = (const float*)d_in[3];
  const float* n1b = (const float*)d_in[4];
  const float* n2w = (const float*)d_in[5];
  const float* n2b = (const float*)d_in[6];
  const float* mw1 = (const float*)d_in[7];
  const float* mb1 = (const float*)d_in[8];
  const float* mw2 = (const float*)d_in[9];
  const float* mb2 = (const float*)d_in[10];
  float* out = (float*)d_out;

  char* ws = (char*)d_ws;
  const size_t MB = 1ull << 20;
  unsigned short* xn  = (unsigned short*)(ws + 0*MB);    // 25.2 MB [b,h,c,w]
  unsigned short* S1  = (unsigned short*)(ws + 26*MB);   // 26 [b,h,m66,c]
  unsigned short* S2  = (unsigned short*)(ws + 53*MB);   // 26 [b2cp,kh,kw,c]
  unsigned short* o1  = (unsigned short*)(ws + 80*MB);   // 26 [b2cp,kw,h,c]
  unsigned short* S3  = (unsigned short*)(ws + 107*MB);  // 25.2 [b,kp,h,c]
  unsigned short* xsb = (unsigned short*)(ws + 133*MB);  // 25.2 bf16 xs
  float2*         stats = (float2*)(ws + 159*MB);        // 256 KB (mu, rs)
  unsigned short* hid = (unsigned short*)(ws + 160*MB);  // 100.7 bf16
  unsigned short* w1t = (unsigned short*)(ws + 261*MB);  // 1.2 bf16 (g-folded)
  unsigned short* w2t = (unsigned short*)(ws + 263*MB);  // 1.2 bf16
  unsigned short* atab = (unsigned short*)(ws + 265*MB);
  float2*         gsbb = (float2*)(ws + 266*MB);

  prep_kernel<<<1222, 256, 0, stream>>>(atab, mw1, w1t, mw2, w2t, n2w, n2b, mb1, gsbb);
  // LN1 + transpose -> bf16
  ln1t_kernel<<<512, 256, 0, stream>>>(x, n1w, n1b, xn);
  // W-fwd
  dft_kernel<0><<<512*3, 256, 0, stream>>>(atab, xn, S1);
  // H-fwd
  dft_kernel<1><<<264*3, 256, 0, stream>>>(atab, S1, S2);
  // block-diag complex matmul + ReLU
  blockmm2_kernel<<<64*WF*4, 384, 0, stream>>>(S2, w1, b1, o1);
  // H-inv
  dft_kernel<2><<<264*3, 256, 0, stream>>>(atab, o1, S3);
  // W-inv -> xs (bf16)
  dft_kernel<3><<<512*3, 256, 0, stream>>>(atab, S3, xsb);
  // LN2 stats
  stats_kernel<<<NTOK/4, 256, 0, stream>>>(xsb, stats);
  // GEMM1: hid = gelu(LN2(xs) @ W1 + b1)  M=32768 N=1536 K=384
  mfma_gemm_kernel<0><<<256*12, 256, 0, stream>>>(xsb, 384, w1t, 384,
                                                  hid, 1536, 384, 12,
                                                  stats, gsbb, nullptr, nullptr, nullptr);
  // GEMM2: out = hid @ W2 + xs + x + b2  M=32768 N=384 K=1536
  mfma_gemm_kernel<1><<<256*3, 256, 0, stream>>>(hid, 1536, w2t, 1536,
                                                 out, 384, 1536, 3,
                                                 nullptr, nullptr, xsb, x, mb2);
}

// Round 12
// 356.553 us; speedup vs baseline: 1.1331x; 1.1331x over previous
//
#include <hip/hip_runtime.h>
#include <math.h>

// AFNO block, MI355X. Spectral path: bf16 MFMA DFT stages vs constant twiddle
// tables. MLP: bf16 MFMA GEMMs, BK=32 2-phase (GEMM1: LN2-affine + tanh-GELU
// epilogue -> bf16 hid; GEMM2: residual+bias epilogue). prep merged with LN1.
// 9 launches.

#define BB 8
#define CC 384
#define WF 33
#define NBK 8
#define BSZ 48
#define NTOK 32768
#define TW64 0.09817477042468103f  // 2*pi/64

#define T_AWF 0
#define T_AHF 5120
#define T_AHI 21504
#define T_AWI 37888

typedef __attribute__((ext_vector_type(8))) short bf16x8;
typedef __attribute__((ext_vector_type(4))) float f32x4;

__device__ __forceinline__ unsigned short f2b(float f) {
  union { float f; unsigned u; } x; x.f = f;
  unsigned u = x.u;
  return (unsigned short)((u + 0x7fffu + ((u >> 16) & 1u)) >> 16);
}
__device__ __forceinline__ float b2fl(unsigned short u) {
  return __uint_as_float(((unsigned)u) << 16);
}
__device__ __forceinline__ void gload16(const void* g, void* l) {
  __builtin_amdgcn_global_load_lds(
      (const __attribute__((address_space(1))) void*)g,
      (__attribute__((address_space(3))) void*)l, 16, 0, 0);
}
// tanh-approx GELU: v*sigmoid(2*0.79788456*(v+0.044715 v^3)).
// |err vs exact erf-GELU| < ~3e-4 — below bf16 resolution of hid.
__device__ __forceinline__ float gelu_fast(float v) {
  float z = 2.3022082f*v + 0.1029433f*v*v*v;   // 2*inner/ln2
  z = fminf(fmaxf(z, -36.f), 36.f);
  float e = exp2f(z);
  return v * e * __builtin_amdgcn_rcpf(e + 1.f);
}

// ---------------- merged: LN1+transpose (bid<512) and prep (bid>=512) ----------
__global__ __launch_bounds__(256) void prep_ln1_kernel(
    const float* __restrict__ x, const float* __restrict__ n1w,
    const float* __restrict__ n1b, unsigned short* __restrict__ xn,
    unsigned short* __restrict__ A,
    const float* __restrict__ mw1, unsigned short* __restrict__ w1t,
    const float* __restrict__ mw2, unsigned short* __restrict__ w2t,
    const float* __restrict__ n2w, const float* __restrict__ n2b,
    const float* __restrict__ mb1, float2* __restrict__ gsbb) {
  __shared__ float tile[32][33];
  int bid0 = blockIdx.x;
  if (bid0 < 512) {
    // ---- LN1 fused with transpose: x[b,h,w,c] -> xn[b,h,c,w] bf16 ----
    int outer = bid0;  // b*64+h
    int tid = threadIdx.x, lane = tid & 63, wg = tid >> 6;
    const float* base = x + (size_t)outer * 64 * 384;
    float s[16], s2[16];
#pragma unroll
    for (int q = 0; q < 16; ++q) { s[q] = 0.f; s2[q] = 0.f; }
    for (int ch = 0; ch < 6; ++ch) {
#pragma unroll
      for (int q = 0; q < 16; ++q) {
        float v = base[(size_t)(wg*16 + q)*384 + ch*64 + lane];
        s[q] += v; s2[q] += v*v;
      }
    }
#pragma unroll
    for (int q = 0; q < 16; ++q) {
#pragma unroll
      for (int off = 32; off >= 1; off >>= 1) {
        s[q] += __shfl_xor(s[q], off);
        s2[q] += __shfl_xor(s2[q], off);
      }
    }
    float mu[16], rs[16];
#pragma unroll
    for (int q = 0; q < 16; ++q) {
      mu[q] = s[q] * (1.f/384.f);
      rs[q] = rsqrtf(s2[q] * (1.f/384.f) - mu[q]*mu[q] + 1e-5f);
    }
    unsigned short* o = xn + (size_t)outer * 384 * 64;
    for (int ch = 0; ch < 6; ++ch) {
      int c = ch*64 + lane;
      float ga = n1w[c], bb2 = n1b[c];
#pragma unroll
      for (int qq = 0; qq < 4; ++qq) {
        unsigned short hv[4];
#pragma unroll
        for (int r2 = 0; r2 < 4; ++r2) {
          int q = qq*4 + r2;
          hv[r2] = f2b((base[(size_t)(wg*16+q)*384 + c]-mu[q])*rs[q]*ga + bb2);
        }
        uint2 pw;
        pw.x = hv[0] | ((unsigned)hv[1] << 16);
        pw.y = hv[2] | ((unsigned)hv[3] << 16);
        *(uint2*)(o + (size_t)c*64 + wg*16 + qq*4) = pw;
      }
    }
    return;
  }
  int bid = bid0 - 512;
  if (bid < 64) {
    int idx0 = bid * 256 + threadIdx.x;
    const float S = 0.125f;
    for (int e = idx0; e < 5120; e += 16384) {
      int m = e >> 6, w = e & 63;
      float val = 0.f;
      if (m < 66) {
        int kwv = m >> 1;
        float th = (float)((kwv * w) & 63) * TW64;
        val = (m & 1) ? (((kwv==0)||(kwv==32)) ? 0.f : -sinf(th)*S) : cosf(th)*S;
      }
      A[T_AWF + e] = f2b(val);
    }
    for (int e = idx0; e < 16384; e += 16384) {
      int comp = e >> 13; int r = e & 8191; int mp = r >> 6, hh = r & 63;
      int cpo = mp >> 6, kh = mp & 63;
      float th = (float)((kh * hh) & 63) * TW64;
      float cv = cosf(th), sv = sinf(th);
      float fv = (cpo == 0) ? (comp == 0 ? cv : sv) : (comp == 0 ? -sv : cv);
      A[T_AHF + e] = f2b(fv * S);
      float iv = (cpo == 0) ? (comp == 0 ? cv : -sv) : (comp == 0 ? sv : cv);
      A[T_AHI + e] = f2b(iv * S);
    }
    for (int e = idx0; e < 4096; e += 16384) {
      int w = e >> 6, kp = e & 63;
      float val;
      if (kp <= 32) {
        float th = (float)((kp * w) & 63) * TW64;
        val = cosf(th) * (((kp==0)||(kp==32)) ? 1.f : 2.f) * S;
      } else {
        int k2 = kp - 32;
        float th = (float)((k2 * w) & 63) * TW64;
        val = -2.f * sinf(th) * S;
      }
      A[T_AWI + e] = f2b(val);
    }
    return;
  }
  if (bid >= 1216) {
    int n0 = (bid - 1216) * 256 + threadIdx.x;
    if (n0 < 1536) {
      float gsv = 0.f, bbv = 0.f;
      for (int k = 0; k < 384; ++k) {
        float a = mw1[(size_t)k*1536 + n0];
        gsv += n2w[k]*a;
        bbv += n2b[k]*a;
      }
      gsbb[n0] = make_float2(gsv, bbv + mb1[n0]);
    }
    return;
  }
  int tx = threadIdx.x & 31, ty = threadIdx.x >> 5;
  if (bid < 640) {
    // mw1 (384x1536) -> w1t [n][k] bf16, fold n2w into k
    int tb = bid - 64;
    int ntc = 1536 >> 5;
    int bx = tb % ntc, by = tb / ntc;
    for (int rr2 = ty; rr2 < 32; rr2 += 8)
      tile[rr2][tx] = mw1[(size_t)(by*32+rr2)*1536 + bx*32 + tx];
    __syncthreads();
    float gv = n2w[by*32 + tx];
    for (int rr2 = ty; rr2 < 32; rr2 += 8)
      w1t[(size_t)(bx*32+rr2)*384 + by*32 + tx] = f2b(tile[tx][rr2] * gv);
  } else {
    // mw2 (1536x384) -> w2t [n][k] bf16
    int tb = bid - 640;
    int ntc = 384 >> 5;
    int bx = tb % ntc, by = tb / ntc;
    for (int rr2 = ty; rr2 < 32; rr2 += 8)
      tile[rr2][tx] = mw2[(size_t)(by*32+rr2)*384 + bx*32 + tx];
    __syncthreads();
    for (int rr2 = ty; rr2 < 32; rr2 += 8)
      w2t[(size_t)(bx*32+rr2)*1536 + by*32 + tx] = f2b(tile[tx][rr2]);
  }
}

// ---------------- DFT stage as MFMA GEMM (single bf16 plane) -------------------
// STAGE: 0=W-fwd, 1=H-fwd, 2=H-inv, 3=W-inv (all write bf16 to O)
template<int STAGE>
__global__ __launch_bounds__(256) void dft_kernel(
    const unsigned short* __restrict__ A0, const unsigned short* __restrict__ D,
    unsigned short* __restrict__ O) {
  constexpr int M = (STAGE==0) ? 80 : (STAGE==3) ? 64 : 128;
  constexpr int MT = M / 16;
  constexpr int NA = (STAGE==1 || STAGE==2) ? 2 : 1;
  constexpr int ABYTES = NA * M * 128;
  constexpr int STG2 = ABYTES + 16384;
  constexpr int EPB = 64 * 128 * 4;
  constexpr int SB = (STG2 > EPB) ? STG2 : EPB;
  __shared__ __align__(16) char smem[SB];
  char* BPL = smem + ABYTES;

  int bid = blockIdx.x;
  int cc = bid % 3; int outer = bid / 3;
  int c0 = cc * 128;
  int tid = threadIdx.x, lane = tid & 63, wid = tid >> 6;
  int rr = lane & 15, rq = lane >> 4;
  int b, h = 0, kw = 0;
  if (STAGE == 0 || STAGE == 3) { b = outer >> 6; h = outer & 63; }
  else { b = outer / 33; kw = outer % 33; }

  f32x4 acc[MT][2];
#pragma unroll
  for (int mt = 0; mt < MT; ++mt)
#pragma unroll
    for (int nt = 0; nt < 2; ++nt) acc[mt][nt] = (f32x4){0.f,0.f,0.f,0.f};

  const unsigned short* Atab =
    (STAGE==0) ? A0+T_AWF : (STAGE==1) ? A0+T_AHF : (STAGE==2) ? A0+T_AHI : A0+T_AWI;
  constexpr int ACH = NA * M * 8;
#pragma unroll
  for (int i = 0; i < (ACH + 255)/256; ++i) {
    int t2 = tid + i*256;
    if ((ACH % 256 == 0) || (t2 < ACH)) {
      int mm = t2 >> 3, ch = t2 & 7;
      gload16(Atab + mm*64 + ((ch ^ (mm & 7)) << 3), smem + i*4096 + wid*1024);
    }
  }

  int ncomp = (STAGE == 1) ? ((kw == 0 || kw == 32) ? 1 : 2) : NA;

  for (int comp = 0; comp < ncomp; ++comp) {
    if (comp) __syncthreads();
    if (STAGE == 0) {
      const unsigned short* src = D + (((size_t)(b*64 + h))*384 + c0) * 64;
#pragma unroll
      for (int i = 0; i < 4; ++i) {
        int idx = tid + i*256;
        int c = idx >> 3, ch = idx & 7;
        gload16(src + c*64 + ((ch ^ (c & 7)) << 3), BPL + i*4096 + wid*1024);
      }
    } else {
      size_t P; int RS;
      if (STAGE == 1) { P = (size_t)b*(64*66*384) + (size_t)(2*kw + comp)*384 + c0; RS = 66*384; }
      else if (STAGE == 2) { P = ((size_t)((b*2 + comp)*33) + kw)*64*384 + c0; RS = 384; }
      else { P = (size_t)b*(64*64*384) + (size_t)h*384 + c0; RS = 64*384; }
      const unsigned short* p0 = D + P;
#pragma unroll
      for (int i = 0; i < 4; ++i) {
        int kq = (tid >> 6) + i*4;
        int c2 = (tid & 63) * 2;
        const unsigned short* p = p0 + (size_t)(4*kq)*RS + c2;
        unsigned u0 = *(const unsigned*)p;
        unsigned u1 = *(const unsigned*)(p + RS);
        unsigned u2 = *(const unsigned*)(p + 2*(size_t)RS);
        unsigned u3 = *(const unsigned*)(p + 3*(size_t)RS);
        uint2 w0, w1v;
        w0.x = (u0 & 0xffffu) | (u1 << 16);
        w0.y = (u2 & 0xffffu) | (u3 << 16);
        w1v.x = (u0 >> 16) | (u1 & 0xffff0000u);
        w1v.y = (u2 >> 16) | (u3 & 0xffff0000u);
        *(uint2*)(BPL + c2*128 + ((kq*8) ^ ((c2 & 7) << 4))) = w0;
        *(uint2*)(BPL + (c2+1)*128 + ((kq*8) ^ (((c2+1) & 7) << 4))) = w1v;
      }
    }
    __syncthreads();
#pragma unroll
    for (int kh2 = 0; kh2 < 2; ++kh2) {
      int chb = kh2*4 + rq;
      bf16x8 bfr[2];
#pragma unroll
      for (int nt = 0; nt < 2; ++nt) {
        int n = wid*32 + nt*16 + rr;
        bfr[nt] = *(const bf16x8*)(BPL + n*128 + ((chb ^ (n & 7)) << 4));
      }
#pragma unroll
      for (int mt = 0; mt < MT; ++mt) {
        int mr = mt*16 + rr;
        bf16x8 af = *(const bf16x8*)(smem + comp*(M*128) + mr*128 + ((chb ^ (mr & 7)) << 4));
#pragma unroll
        for (int nt = 0; nt < 2; ++nt)
          acc[mt][nt] = __builtin_amdgcn_mfma_f32_16x16x32_bf16(af, bfr[nt], acc[mt][nt], 0, 0, 0);
      }
    }
  }
  __syncthreads();

  float* ep = (float*)smem;
  constexpr int NHM = (M + 63) / 64;
#pragma unroll
  for (int hm = 0; hm < NHM; ++hm) {
    if (hm) __syncthreads();
#pragma unroll
    for (int mo = 0; mo < 4; ++mo) {
      int mt = hm*4 + mo;
      if (mt >= MT) break;
#pragma unroll
      for (int nt = 0; nt < 2; ++nt)
#pragma unroll
        for (int j = 0; j < 4; ++j) {
          int m2 = mo*16 + rq*4 + j;
          int cl = wid*32 + nt*16 + rr;
          ep[m2*128 + (cl ^ ((m2 & 7) << 2))] = acc[mt][nt][j];
        }
    }
    __syncthreads();
    for (int it = tid; it < 64*16; it += 256) {
      int m2 = it >> 4, u8 = it & 15;
      int m = hm*64 + m2;
      if (m >= M) break;
      if (STAGE == 0 && m >= 66) break;
      if (STAGE == 2) { int cp = m >> 6; if (cp && (kw == 0 || kw == 32)) continue; }
      int swz = (m2 & 7) << 2;
      float4 v0 = *(const float4*)(ep + m2*128 + ((u8*8) ^ swz));
      float4 v1 = *(const float4*)(ep + m2*128 + ((u8*8 + 4) ^ swz));
      uint4 pw;
      pw.x = f2b(v0.x) | ((unsigned)f2b(v0.y) << 16);
      pw.y = f2b(v0.z) | ((unsigned)f2b(v0.w) << 16);
      pw.z = f2b(v1.x) | ((unsigned)f2b(v1.y) << 16);
      pw.w = f2b(v1.z) | ((unsigned)f2b(v1.w) << 16);
      size_t rowb;
      if (STAGE == 0) rowb = ((size_t)(b*64 + h)*66 + m)*384 + c0;
      else if (STAGE == 1) { int cp = m >> 6, kh = m & 63;
        rowb = (((size_t)((b*2 + cp)*64 + kh)*33) + kw)*384 + c0; }
      else if (STAGE == 2) { int cp = m >> 6, h2 = m & 63; int kp = cp ? 32 + kw : kw;
        rowb = ((size_t)(b*64 + kp)*64 + h2)*384 + c0; }
      else rowb = ((size_t)(b*64 + h)*64 + m)*384 + c0;
      *(uint4*)(O + rowb + u8*8) = pw;
    }
  }
}

// ---------------- block-diag complex matmul + ReLU: 2 modes/block --------------
__global__ __launch_bounds__(384) void blockmm2_kernel(
    const unsigned short* __restrict__ S2, const float* __restrict__ w1,
    const float* __restrict__ b1, unsigned short* __restrict__ o1) {
  int bid = blockIdx.x;
  int np = bid % 4;
  int kw = (bid / 4) % WF;
  int h = bid / (4*WF);
  int tid = threadIdx.x;
  __shared__ float4 wl4[2][48*24];
  __shared__ float2 xl[2][BB][48];
  __shared__ float2 bl[2][48];
#pragma unroll
  for (int e = tid; e < 2304; e += 384) {
    int sub = e / 1152, r = e % 1152;
    const float4* wb4 = (const float4*)(w1 + ((size_t)((h*WF + kw)*NBK) + 2*np + sub)*(BSZ*BSZ*2));
    wl4[sub][r] = wb4[r];
  }
  if (tid < 96) {
    int sub = tid / 48, o = tid % 48;
    bl[sub][o] = ((const float2*)b1)[((size_t)((h*WF + kw)*NBK) + 2*np + sub)*BSZ + o];
  }
#pragma unroll
  for (int e = tid; e < 768; e += 384) {
    int sub = e / 384, r = e % 384, bb = r / 48, i = r % 48;
    int n = 2*np + sub;
    size_t ir = (((size_t)((bb*2 + 0)*64 + h)*33) + kw)*384 + n*48 + i;
    size_t ii = (((size_t)((bb*2 + 1)*64 + h)*33) + kw)*384 + n*48 + i;
    xl[sub][bb][i] = make_float2(b2fl(S2[ir]), b2fl(S2[ii]));
  }
  __syncthreads();
  int sub = tid / 192, r = tid % 192, bb = r / 24, o2 = r % 24;
  float4 bv = *(const float4*)(&bl[sub][2*o2]);
  float2 a0 = make_float2(bv.x, bv.y);
  float2 a1 = make_float2(bv.z, bv.w);
#pragma unroll
  for (int i = 0; i < 48; ++i) {
    float2 xv = xl[sub][bb][i];
    float4 wv = wl4[sub][i*24 + o2];
    a0.x += xv.x*wv.x - xv.y*wv.y;
    a0.y += xv.x*wv.y + xv.y*wv.x;
    a1.x += xv.x*wv.z - xv.y*wv.w;
    a1.y += xv.x*wv.w + xv.y*wv.z;
  }
  int n = 2*np + sub;
  size_t idr = (((size_t)((bb*2 + 0)*33) + kw)*64 + h)*384 + n*48 + 2*o2;
  size_t idi = (((size_t)((bb*2 + 1)*33) + kw)*64 + h)*384 + n*48 + 2*o2;
  *(unsigned*)(o1 + idr) = f2b(fmaxf(a0.x, 0.f)) | ((unsigned)f2b(fmaxf(a1.x, 0.f)) << 16);
  *(unsigned*)(o1 + idi) = f2b(fmaxf(a0.y, 0.f)) | ((unsigned)f2b(fmaxf(a1.y, 0.f)) << 16);
}

// ---------------- LN2 stats: per-token (mu, rs) from xsb ------------------------
__global__ __launch_bounds__(256) void stats_kernel(const unsigned short* __restrict__ in,
    float2* __restrict__ stats) {
  int token = blockIdx.x * 4 + (threadIdx.x >> 6);
  int lane = threadIdx.x & 63;
  const unsigned short* row = in + (size_t)token * CC;
  float s = 0.f, s2 = 0.f;
#pragma unroll
  for (int j = 0; j < 6; ++j) {
    float v = b2fl(row[lane + 64*j]);
    s += v; s2 += v*v;
  }
#pragma unroll
  for (int off = 32; off >= 1; off >>= 1) {
    s += __shfl_xor(s, off);
    s2 += __shfl_xor(s2, off);
  }
  if (lane == 0) {
    float mu = s * (1.0f/CC);
    float rs = rsqrtf(s2 * (1.0f/CC) - mu*mu + 1e-5f);
    stats[token] = make_float2(mu, rs);
  }
}

// ---------------- bf16 MFMA GEMM, BK=32 double-buffered 2-phase ----------------
// MODE 0: v = rs*acc - rs*mu*gs[n] + bb[n]; tanh-GELU; bf16 store (GEMM1)
// MODE 1: out = acc + xs(bf16) + x + b2, fp32 (GEMM2, residual fused)
template<int MODE>
__global__ __launch_bounds__(256) void mfma_gemm_kernel(
    const unsigned short* __restrict__ A, int lda,
    const unsigned short* __restrict__ BT, int ldbt,
    void* __restrict__ Cp, int ldc, int K, int ntn,
    const float2* __restrict__ stats, const float2* __restrict__ gsbb,
    const unsigned short* __restrict__ xsb, const float* __restrict__ xres,
    const float* __restrict__ b2v) {
  __shared__ __align__(16) char gsm[32768];  // 2 bufs x (A 8KB + B 8KB)
  int nb = (int)gridDim.x;
  int bidx = (int)blockIdx.x;
  int bswz = (bidx & 7) * (nb >> 3) + (bidx >> 3);
  int bn = bswz % ntn;
  int bm = bswz / ntn;
  int t = threadIdx.x;
  int lane = t & 63;
  int wid = t >> 6;
  int wm = wid >> 1, wn = wid & 1;
  int rr = lane & 15, rq = lane >> 4;

  f32x4 acc[4][4];
#pragma unroll
  for (int m = 0; m < 4; ++m)
#pragma unroll
    for (int n = 0; n < 4; ++n) acc[m][n] = (f32x4){0.f,0.f,0.f,0.f};

  const unsigned short* Abase = A + (size_t)bm*128*lda;
  const unsigned short* Bbase = BT + (size_t)bn*128*ldbt;
  int nt = K >> 5;

#define STG(bsel, t0)                                                        \
  {                                                                          \
    _Pragma("unroll")                                                        \
    for (int i = 0; i < 2; ++i) {                                            \
      int u = t + i*256;                                                     \
      int row = u >> 2, ch = u & 3;                                          \
      gload16(Abase + (size_t)row*lda + (t0)*32 + ((ch ^ (row & 3)) << 3),   \
              gsm + (bsel)*16384 + i*4096 + wid*1024);                       \
      gload16(Bbase + (size_t)row*ldbt + (t0)*32 + ((ch ^ (row & 3)) << 3),  \
              gsm + (bsel)*16384 + 8192 + i*4096 + wid*1024);                \
    }                                                                        \
  }

#define CMP(bsel)                                                            \
  {                                                                          \
    const char* Ab2 = gsm + (bsel)*16384;                                    \
    const char* Bb2 = Ab2 + 8192;                                            \
    bf16x8 af[4], bfv[4];                                                    \
    _Pragma("unroll")                                                        \
    for (int m = 0; m < 4; ++m) {                                            \
      int row = wm*64 + m*16 + rr;                                           \
      af[m] = *(const bf16x8*)(Ab2 + row*64 + ((rq ^ (row & 3)) << 4));      \
    }                                                                        \
    _Pragma("unroll")                                                        \
    for (int n = 0; n < 4; ++n) {                                            \
      int row = wn*64 + n*16 + rr;                                           \
      bfv[n] = *(const bf16x8*)(Bb2 + row*64 + ((rq ^ (row & 3)) << 4));     \
    }                                                                        \
    _Pragma("unroll")                                                        \
    for (int m = 0; m < 4; ++m)                                              \
      _Pragma("unroll")                                                      \
      for (int n = 0; n < 4; ++n)                                            \
        acc[m][n] = __builtin_amdgcn_mfma_f32_16x16x32_bf16(af[m], bfv[n], acc[m][n], 0, 0, 0); \
  }

  STG(0, 0);
  __syncthreads();
  int cur = 0;
  for (int tt = 0; tt < nt - 1; ++tt) {
    STG(cur ^ 1, tt + 1);
    CMP(cur);
    __syncthreads();
    cur ^= 1;
  }
  CMP(cur);
  __syncthreads();
#undef STG
#undef CMP

  if (MODE == 0) {
    // LN2-affine + tanh-GELU, bf16 store via LDS repack
    unsigned short* ep = (unsigned short*)gsm;
#pragma unroll
    for (int m = 0; m < 4; ++m) {
      float2 st[4];
#pragma unroll
      for (int j = 0; j < 4; ++j)
        st[j] = stats[bm*128 + wm*64 + m*16 + rq*4 + j];
#pragma unroll
      for (int n = 0; n < 4; ++n) {
        int lcol = wn*64 + n*16 + rr;
        float2 gb = gsbb[bn*128 + lcol];
#pragma unroll
        for (int j = 0; j < 4; ++j) {
          float v = st[j].y * acc[m][n][j] - st[j].y * st[j].x * gb.x + gb.y;
          v = gelu_fast(v);
          int row = wm*64 + m*16 + rq*4 + j;
          ep[row*128 + (lcol ^ ((row & 7) << 3))] = f2b(v);
        }
      }
    }
    __syncthreads();
    for (int it = t; it < 128*16; it += 256) {
      int m = it >> 4, u8 = it & 15;
      uint4 pw = *(const uint4*)(ep + m*128 + ((u8*8) ^ ((m & 7) << 3)));
      *(uint4*)((unsigned short*)Cp + (size_t)(bm*128 + m)*ldc + bn*128 + u8*8) = pw;
    }
  } else {
    // out = acc + xs(bf16) + x + b2, fp32, via 2-half LDS repack
    float* ep = (float*)gsm;
#pragma unroll
    for (int half = 0; half < 2; ++half) {
      __syncthreads();
#pragma unroll
      for (int mo = 0; mo < 2; ++mo) {
        int m = half*2 + mo;
#pragma unroll
        for (int n = 0; n < 4; ++n)
#pragma unroll
          for (int j = 0; j < 4; ++j) {
            int lr = wm*32 + mo*16 + rq*4 + j;
            int col = wn*64 + n*16 + rr;
            ep[lr*128 + (col ^ ((lr & 7) << 2))] = acc[m][n][j];
          }
      }
      __syncthreads();
      for (int it = t; it < 64*32; it += 256) {
        int lr = it >> 5, u = it & 31;
        int swz = (lr & 7) << 2;
        float4 v = *(const float4*)(ep + lr*128 + ((u*4) ^ swz));
        int grow = bm*128 + (lr >> 5)*64 + (half*2 + ((lr >> 4) & 1))*16 + (lr & 15);
        int gcol = bn*128 + u*4;
        size_t idx = (size_t)grow*ldc + gcol;
        float4 xr = *(const float4*)(xres + idx);
        uint2 xsv = *(const uint2*)(xsb + idx);
        float4 bv = *(const float4*)(b2v + gcol);
        float4 ov;
        ov.x = v.x + xr.x + b2fl((unsigned short)(xsv.x & 0xffffu)) + bv.x;
        ov.y = v.y + xr.y + b2fl((unsigned short)(xsv.x >> 16)) + bv.y;
        ov.z = v.z + xr.z + b2fl((unsigned short)(xsv.y & 0xffffu)) + bv.z;
        ov.w = v.w + xr.w + b2fl((unsigned short)(xsv.y >> 16)) + bv.w;
        *(float4*)((float*)Cp + idx) = ov;
      }
    }
  }
}

extern "C" void kernel_launch(void* const* d_in, const int* in_sizes, int n_in,
                              void* d_out, int out_size, void* d_ws, size_t ws_size,
                              hipStream_t stream) {
  const float* x   = (const float*)d_in[0];
  const float* w1  = (const float*)d_in[1];
  const float* b1  = (const float*)d_in[2];
  const float* n1w = (const float*)d_in[3];
  const float* n1b = (const float*)d_in[4];
  const float* n2w = (const float*)d_in[5];
  const float* n2b = (const float*)d_in[6];
  const float* mw1 = (const float*)d_in[7];
  const float* mb1 = (const float*)d_in[8];
  const float* mw2 = (const float*)d_in[9];
  const float* mb2 = (const float*)d_in[10];
  float* out = (float*)d_out;

  char* ws = (char*)d_ws;
  const size_t MB = 1ull << 20;
  unsigned short* xn  = (unsigned short*)(ws + 0*MB);    // 25.2 MB [b,h,c,w]
  unsigned short* S1  = (unsigned short*)(ws + 26*MB);   // 26 [b,h,m66,c]
  unsigned short* S2  = (unsigned short*)(ws + 53*MB);   // 26 [b2cp,kh,kw,c]
  unsigned short* o1  = (unsigned short*)(ws + 80*MB);   // 26 [b2cp,kw,h,c]
  unsigned short* S3  = (unsigned short*)(ws + 107*MB);  // 25.2 [b,kp,h,c]
  unsigned short* xsb = (unsigned short*)(ws + 133*MB);  // 25.2 bf16 xs
  float2*         stats = (float2*)(ws + 159*MB);        // 256 KB (mu, rs)
  unsigned short* hid = (unsigned short*)(ws + 160*MB);  // 100.7 bf16
  unsigned short* w1t = (unsigned short*)(ws + 261*MB);  // 1.2 bf16 (g-folded)
  unsigned short* w2t = (unsigned short*)(ws + 263*MB);  // 1.2 bf16
  unsigned short* atab = (unsigned short*)(ws + 265*MB);
  float2*         gsbb = (float2*)(ws + 266*MB);

  // merged LN1 (blocks 0..511) + prep (blocks 512..1733)
  prep_ln1_kernel<<<1734, 256, 0, stream>>>(x, n1w, n1b, xn,
                                            atab, mw1, w1t, mw2, w2t,
                                            n2w, n2b, mb1, gsbb);
  // W-fwd
  dft_kernel<0><<<512*3, 256, 0, stream>>>(atab, xn, S1);
  // H-fwd
  dft_kernel<1><<<264*3, 256, 0, stream>>>(atab, S1, S2);
  // block-diag complex matmul + ReLU
  blockmm2_kernel<<<64*WF*4, 384, 0, stream>>>(S2, w1, b1, o1);
  // H-inv
  dft_kernel<2><<<264*3, 256, 0, stream>>>(atab, o1, S3);
  // W-inv -> xs (bf16)
  dft_kernel<3><<<512*3, 256, 0, stream>>>(atab, S3, xsb);
  // LN2 stats
  stats_kernel<<<NTOK/4, 256, 0, stream>>>(xsb, stats);
  // GEMM1: hid = gelu(LN2(xs) @ W1 + b1)  M=32768 N=1536 K=384
  mfma_gemm_kernel<0><<<256*12, 256, 0, stream>>>(xsb, 384, w1t, 384,
                                                  hid, 1536, 384, 12,
                                                  stats, gsbb, nullptr, nullptr, nullptr);
  // GEMM2: out = hid @ W2 + xs + x + b2  M=32768 N=384 K=1536
  mfma_gemm_kernel<1><<<256*3, 256, 0, stream>>>(hid, 1536, w2t, 1536,
                                                 out, 384, 1536, 3,
                                                 nullptr, nullptr, xsb, x, mb2);
}

// Round 13
// 352.273 us; speedup vs baseline: 1.1469x; 1.0121x over previous
//
#include <hip/hip_runtime.h>
#include <math.h>

// AFNO block, MI355X. Spectral path: bf16 MFMA DFT stages vs constant twiddle
// tables (per-comp A-table staging -> 32KB LDS, 5 blocks/CU). MLP: bf16 MFMA
// GEMMs, BK=32 2-phase (GEMM1: LN2-affine + tanh-GELU epilogue; GEMM2:
// residual+bias epilogue). blockmm streams w1 via nontemporal loads.

#define BB 8
#define CC 384
#define WF 33
#define NBK 8
#define BSZ 48
#define NTOK 32768
#define TW64 0.09817477042468103f  // 2*pi/64

#define T_AWF 0
#define T_AHF 5120
#define T_AHI 21504
#define T_AWI 37888

typedef __attribute__((ext_vector_type(8))) short bf16x8;
typedef __attribute__((ext_vector_type(4))) float f32x4;

__device__ __forceinline__ unsigned short f2b(float f) {
  union { float f; unsigned u; } x; x.f = f;
  unsigned u = x.u;
  return (unsigned short)((u + 0x7fffu + ((u >> 16) & 1u)) >> 16);
}
__device__ __forceinline__ float b2fl(unsigned short u) {
  return __uint_as_float(((unsigned)u) << 16);
}
__device__ __forceinline__ void gload16(const void* g, void* l) {
  __builtin_amdgcn_global_load_lds(
      (const __attribute__((address_space(1))) void*)g,
      (__attribute__((address_space(3))) void*)l, 16, 0, 0);
}
// tanh-approx GELU (err < ~3e-4, below bf16 resolution of hid)
__device__ __forceinline__ float gelu_fast(float v) {
  float z = 2.3022082f*v + 0.1029433f*v*v*v;
  z = fminf(fmaxf(z, -36.f), 36.f);
  float e = exp2f(z);
  return v * e * __builtin_amdgcn_rcpf(e + 1.f);
}

// ---------------- merged: LN1+transpose (bid<512) and prep (bid>=512) ----------
__global__ __launch_bounds__(256) void prep_ln1_kernel(
    const float* __restrict__ x, const float* __restrict__ n1w,
    const float* __restrict__ n1b, unsigned short* __restrict__ xn,
    unsigned short* __restrict__ A,
    const float* __restrict__ mw1, unsigned short* __restrict__ w1t,
    const float* __restrict__ mw2, unsigned short* __restrict__ w2t,
    const float* __restrict__ n2w, const float* __restrict__ n2b,
    const float* __restrict__ mb1, float2* __restrict__ gsbb) {
  __shared__ float tile[32][33];
  int bid0 = blockIdx.x;
  if (bid0 < 512) {
    int outer = bid0;  // b*64+h
    int tid = threadIdx.x, lane = tid & 63, wg = tid >> 6;
    const float* base = x + (size_t)outer * 64 * 384;
    float s[16], s2[16];
#pragma unroll
    for (int q = 0; q < 16; ++q) { s[q] = 0.f; s2[q] = 0.f; }
    for (int ch = 0; ch < 6; ++ch) {
#pragma unroll
      for (int q = 0; q < 16; ++q) {
        float v = base[(size_t)(wg*16 + q)*384 + ch*64 + lane];
        s[q] += v; s2[q] += v*v;
      }
    }
#pragma unroll
    for (int q = 0; q < 16; ++q) {
#pragma unroll
      for (int off = 32; off >= 1; off >>= 1) {
        s[q] += __shfl_xor(s[q], off);
        s2[q] += __shfl_xor(s2[q], off);
      }
    }
    float mu[16], rs[16];
#pragma unroll
    for (int q = 0; q < 16; ++q) {
      mu[q] = s[q] * (1.f/384.f);
      rs[q] = rsqrtf(s2[q] * (1.f/384.f) - mu[q]*mu[q] + 1e-5f);
    }
    unsigned short* o = xn + (size_t)outer * 384 * 64;
    for (int ch = 0; ch < 6; ++ch) {
      int c = ch*64 + lane;
      float ga = n1w[c], bb2 = n1b[c];
#pragma unroll
      for (int qq = 0; qq < 4; ++qq) {
        unsigned short hv[4];
#pragma unroll
        for (int r2 = 0; r2 < 4; ++r2) {
          int q = qq*4 + r2;
          hv[r2] = f2b((base[(size_t)(wg*16+q)*384 + c]-mu[q])*rs[q]*ga + bb2);
        }
        uint2 pw;
        pw.x = hv[0] | ((unsigned)hv[1] << 16);
        pw.y = hv[2] | ((unsigned)hv[3] << 16);
        *(uint2*)(o + (size_t)c*64 + wg*16 + qq*4) = pw;
      }
    }
    return;
  }
  int bid = bid0 - 512;
  if (bid < 64) {
    int idx0 = bid * 256 + threadIdx.x;
    const float S = 0.125f;
    for (int e = idx0; e < 5120; e += 16384) {
      int m = e >> 6, w = e & 63;
      float val = 0.f;
      if (m < 66) {
        int kwv = m >> 1;
        float th = (float)((kwv * w) & 63) * TW64;
        val = (m & 1) ? (((kwv==0)||(kwv==32)) ? 0.f : -sinf(th)*S) : cosf(th)*S;
      }
      A[T_AWF + e] = f2b(val);
    }
    for (int e = idx0; e < 16384; e += 16384) {
      int comp = e >> 13; int r = e & 8191; int mp = r >> 6, hh = r & 63;
      int cpo = mp >> 6, kh = mp & 63;
      float th = (float)((kh * hh) & 63) * TW64;
      float cv = cosf(th), sv = sinf(th);
      float fv = (cpo == 0) ? (comp == 0 ? cv : sv) : (comp == 0 ? -sv : cv);
      A[T_AHF + e] = f2b(fv * S);
      float iv = (cpo == 0) ? (comp == 0 ? cv : -sv) : (comp == 0 ? sv : cv);
      A[T_AHI + e] = f2b(iv * S);
    }
    for (int e = idx0; e < 4096; e += 16384) {
      int w = e >> 6, kp = e & 63;
      float val;
      if (kp <= 32) {
        float th = (float)((kp * w) & 63) * TW64;
        val = cosf(th) * (((kp==0)||(kp==32)) ? 1.f : 2.f) * S;
      } else {
        int k2 = kp - 32;
        float th = (float)((k2 * w) & 63) * TW64;
        val = -2.f * sinf(th) * S;
      }
      A[T_AWI + e] = f2b(val);
    }
    return;
  }
  if (bid >= 1216) {
    int n0 = (bid - 1216) * 256 + threadIdx.x;
    if (n0 < 1536) {
      float gsv = 0.f, bbv = 0.f;
      for (int k = 0; k < 384; ++k) {
        float a = mw1[(size_t)k*1536 + n0];
        gsv += n2w[k]*a;
        bbv += n2b[k]*a;
      }
      gsbb[n0] = make_float2(gsv, bbv + mb1[n0]);
    }
    return;
  }
  int tx = threadIdx.x & 31, ty = threadIdx.x >> 5;
  if (bid < 640) {
    int tb = bid - 64;
    int ntc = 1536 >> 5;
    int bx = tb % ntc, by = tb / ntc;
    for (int rr2 = ty; rr2 < 32; rr2 += 8)
      tile[rr2][tx] = mw1[(size_t)(by*32+rr2)*1536 + bx*32 + tx];
    __syncthreads();
    float gv = n2w[by*32 + tx];
    for (int rr2 = ty; rr2 < 32; rr2 += 8)
      w1t[(size_t)(bx*32+rr2)*384 + by*32 + tx] = f2b(tile[tx][rr2] * gv);
  } else {
    int tb = bid - 640;
    int ntc = 384 >> 5;
    int bx = tb % ntc, by = tb / ntc;
    for (int rr2 = ty; rr2 < 32; rr2 += 8)
      tile[rr2][tx] = mw2[(size_t)(by*32+rr2)*384 + bx*32 + tx];
    __syncthreads();
    for (int rr2 = ty; rr2 < 32; rr2 += 8)
      w2t[(size_t)(bx*32+rr2)*1536 + by*32 + tx] = f2b(tile[tx][rr2]);
  }
}

// ---------------- DFT stage as MFMA GEMM (per-comp A staging, 32KB LDS) --------
// STAGE: 0=W-fwd, 1=H-fwd, 2=H-inv, 3=W-inv (all write bf16 to O)
template<int STAGE>
__global__ __launch_bounds__(256) void dft_kernel(
    const unsigned short* __restrict__ A0, const unsigned short* __restrict__ D,
    unsigned short* __restrict__ O) {
  constexpr int M = (STAGE==0) ? 80 : (STAGE==3) ? 64 : 128;
  constexpr int MT = M / 16;
  constexpr int ABYTES = M * 128;          // one comp's table
  constexpr int STG2 = ABYTES + 16384;
  constexpr int EPB = 64 * 128 * 4;
  constexpr int SB = (STG2 > EPB) ? STG2 : EPB;
  __shared__ __align__(16) char smem[SB];
  char* BPL = smem + ABYTES;

  int bid = blockIdx.x;
  int cc = bid % 3; int outer = bid / 3;
  int c0 = cc * 128;
  int tid = threadIdx.x, lane = tid & 63, wid = tid >> 6;
  int rr = lane & 15, rq = lane >> 4;
  int b, h = 0, kw = 0;
  if (STAGE == 0 || STAGE == 3) { b = outer >> 6; h = outer & 63; }
  else { b = outer / 33; kw = outer % 33; }

  f32x4 acc[MT][2];
#pragma unroll
  for (int mt = 0; mt < MT; ++mt)
#pragma unroll
    for (int nt = 0; nt < 2; ++nt) acc[mt][nt] = (f32x4){0.f,0.f,0.f,0.f};

  const unsigned short* Atab =
    (STAGE==0) ? A0+T_AWF : (STAGE==1) ? A0+T_AHF : (STAGE==2) ? A0+T_AHI : A0+T_AWI;

  // stage one comp's A table [M][64] into smem (16B-chunk XOR pre-swizzle)
  auto stageA = [&](int comp) {
    const unsigned short* At = Atab + comp * (M * 64);
#pragma unroll
    for (int i = 0; i < (M*8 + 255)/256; ++i) {
      int t2 = tid + i*256;
      if ((M*8) % 256 == 0 || t2 < M*8) {
        int mm = t2 >> 3, ch = t2 & 7;
        gload16(At + mm*64 + ((ch ^ (mm & 7)) << 3), smem + i*4096 + wid*1024);
      }
    }
  };

  int ncomp = (STAGE == 1) ? ((kw == 0 || kw == 32) ? 1 : 2)
            : (STAGE == 2) ? 2 : 1;

  stageA(0);
  for (int comp = 0; comp < ncomp; ++comp) {
    if (comp) { __syncthreads(); stageA(comp); }
    if (STAGE == 0) {
      const unsigned short* src = D + (((size_t)(b*64 + h))*384 + c0) * 64;
#pragma unroll
      for (int i = 0; i < 4; ++i) {
        int idx = tid + i*256;
        int c = idx >> 3, ch = idx & 7;
        gload16(src + c*64 + ((ch ^ (c & 7)) << 3), BPL + i*4096 + wid*1024);
      }
    } else {
      size_t P; int RS;
      if (STAGE == 1) { P = (size_t)b*(64*66*384) + (size_t)(2*kw + comp)*384 + c0; RS = 66*384; }
      else if (STAGE == 2) { P = ((size_t)((b*2 + comp)*33) + kw)*64*384 + c0; RS = 384; }
      else { P = (size_t)b*(64*64*384) + (size_t)h*384 + c0; RS = 64*384; }
      const unsigned short* p0 = D + P;
#pragma unroll
      for (int i = 0; i < 4; ++i) {
        int kq = (tid >> 6) + i*4;
        int c2 = (tid & 63) * 2;
        const unsigned short* p = p0 + (size_t)(4*kq)*RS + c2;
        unsigned u0 = *(const unsigned*)p;
        unsigned u1 = *(const unsigned*)(p + RS);
        unsigned u2 = *(const unsigned*)(p + 2*(size_t)RS);
        unsigned u3 = *(const unsigned*)(p + 3*(size_t)RS);
        uint2 w0, w1v;
        w0.x = (u0 & 0xffffu) | (u1 << 16);
        w0.y = (u2 & 0xffffu) | (u3 << 16);
        w1v.x = (u0 >> 16) | (u1 & 0xffff0000u);
        w1v.y = (u2 >> 16) | (u3 & 0xffff0000u);
        *(uint2*)(BPL + c2*128 + ((kq*8) ^ ((c2 & 7) << 4))) = w0;
        *(uint2*)(BPL + (c2+1)*128 + ((kq*8) ^ (((c2+1) & 7) << 4))) = w1v;
      }
    }
    __syncthreads();
#pragma unroll
    for (int kh2 = 0; kh2 < 2; ++kh2) {
      int chb = kh2*4 + rq;
      bf16x8 bfr[2];
#pragma unroll
      for (int nt = 0; nt < 2; ++nt) {
        int n = wid*32 + nt*16 + rr;
        bfr[nt] = *(const bf16x8*)(BPL + n*128 + ((chb ^ (n & 7)) << 4));
      }
#pragma unroll
      for (int mt = 0; mt < MT; ++mt) {
        int mr = mt*16 + rr;
        bf16x8 af = *(const bf16x8*)(smem + mr*128 + ((chb ^ (mr & 7)) << 4));
#pragma unroll
        for (int nt = 0; nt < 2; ++nt)
          acc[mt][nt] = __builtin_amdgcn_mfma_f32_16x16x32_bf16(af, bfr[nt], acc[mt][nt], 0, 0, 0);
      }
    }
  }
  __syncthreads();

  float* ep = (float*)smem;
  constexpr int NHM = (M + 63) / 64;
#pragma unroll
  for (int hm = 0; hm < NHM; ++hm) {
    if (hm) __syncthreads();
#pragma unroll
    for (int mo = 0; mo < 4; ++mo) {
      int mt = hm*4 + mo;
      if (mt >= MT) break;
#pragma unroll
      for (int nt = 0; nt < 2; ++nt)
#pragma unroll
        for (int j = 0; j < 4; ++j) {
          int m2 = mo*16 + rq*4 + j;
          int cl = wid*32 + nt*16 + rr;
          ep[m2*128 + (cl ^ ((m2 & 7) << 2))] = acc[mt][nt][j];
        }
    }
    __syncthreads();
    for (int it = tid; it < 64*16; it += 256) {
      int m2 = it >> 4, u8 = it & 15;
      int m = hm*64 + m2;
      if (m >= M) break;
      if (STAGE == 0 && m >= 66) break;
      if (STAGE == 2) { int cp = m >> 6; if (cp && (kw == 0 || kw == 32)) continue; }
      int swz = (m2 & 7) << 2;
      float4 v0 = *(const float4*)(ep + m2*128 + ((u8*8) ^ swz));
      float4 v1 = *(const float4*)(ep + m2*128 + ((u8*8 + 4) ^ swz));
      uint4 pw;
      pw.x = f2b(v0.x) | ((unsigned)f2b(v0.y) << 16);
      pw.y = f2b(v0.z) | ((unsigned)f2b(v0.w) << 16);
      pw.z = f2b(v1.x) | ((unsigned)f2b(v1.y) << 16);
      pw.w = f2b(v1.z) | ((unsigned)f2b(v1.w) << 16);
      size_t rowb;
      if (STAGE == 0) rowb = ((size_t)(b*64 + h)*66 + m)*384 + c0;
      else if (STAGE == 1) { int cp = m >> 6, kh = m & 63;
        rowb = (((size_t)((b*2 + cp)*64 + kh)*33) + kw)*384 + c0; }
      else if (STAGE == 2) { int cp = m >> 6, h2 = m & 63; int kp = cp ? 32 + kw : kw;
        rowb = ((size_t)(b*64 + kp)*64 + h2)*384 + c0; }
      else rowb = ((size_t)(b*64 + h)*64 + m)*384 + c0;
      *(uint4*)(O + rowb + u8*8) = pw;
    }
  }
}

// ---------------- block-diag complex matmul + ReLU: 2 modes/block --------------
__global__ __launch_bounds__(384) void blockmm2_kernel(
    const unsigned short* __restrict__ S2, const float* __restrict__ w1,
    const float* __restrict__ b1, unsigned short* __restrict__ o1) {
  int bid = blockIdx.x;
  int np = bid % 4;
  int kw = (bid / 4) % WF;
  int h = bid / (4*WF);
  int tid = threadIdx.x;
  __shared__ float4 wl4[2][48*24];
  __shared__ float2 xl[2][BB][48];
  __shared__ float2 bl[2][48];
  // stage weights via nontemporal loads (single-use 311 MB stream - keep L3 clean)
#pragma unroll
  for (int e = tid; e < 2304; e += 384) {
    int sub = e / 1152, r = e % 1152;
    const f32x4* wb4 = (const f32x4*)(w1 + ((size_t)((h*WF + kw)*NBK) + 2*np + sub)*(BSZ*BSZ*2));
    f32x4 v = __builtin_nontemporal_load(wb4 + r);
    *(f32x4*)&wl4[sub][r] = v;
  }
  if (tid < 96) {
    int sub = tid / 48, o = tid % 48;
    bl[sub][o] = ((const float2*)b1)[((size_t)((h*WF + kw)*NBK) + 2*np + sub)*BSZ + o];
  }
#pragma unroll
  for (int e = tid; e < 768; e += 384) {
    int sub = e / 384, r = e % 384, bb = r / 48, i = r % 48;
    int n = 2*np + sub;
    size_t ir = (((size_t)((bb*2 + 0)*64 + h)*33) + kw)*384 + n*48 + i;
    size_t ii = (((size_t)((bb*2 + 1)*64 + h)*33) + kw)*384 + n*48 + i;
    xl[sub][bb][i] = make_float2(b2fl(S2[ir]), b2fl(S2[ii]));
  }
  __syncthreads();
  int sub = tid / 192, r = tid % 192, bb = r / 24, o2 = r % 24;
  float4 bv = *(const float4*)(&bl[sub][2*o2]);
  float2 a0 = make_float2(bv.x, bv.y);
  float2 a1 = make_float2(bv.z, bv.w);
#pragma unroll
  for (int i = 0; i < 48; ++i) {
    float2 xv = xl[sub][bb][i];
    float4 wv = wl4[sub][i*24 + o2];
    a0.x += xv.x*wv.x - xv.y*wv.y;
    a0.y += xv.x*wv.y + xv.y*wv.x;
    a1.x += xv.x*wv.z - xv.y*wv.w;
    a1.y += xv.x*wv.w + xv.y*wv.z;
  }
  int n = 2*np + sub;
  size_t idr = (((size_t)((bb*2 + 0)*33) + kw)*64 + h)*384 + n*48 + 2*o2;
  size_t idi = (((size_t)((bb*2 + 1)*33) + kw)*64 + h)*384 + n*48 + 2*o2;
  *(unsigned*)(o1 + idr) = f2b(fmaxf(a0.x, 0.f)) | ((unsigned)f2b(fmaxf(a1.x, 0.f)) << 16);
  *(unsigned*)(o1 + idi) = f2b(fmaxf(a0.y, 0.f)) | ((unsigned)f2b(fmaxf(a1.y, 0.f)) << 16);
}

// ---------------- LN2 stats: per-token (mu, rs) from xsb ------------------------
__global__ __launch_bounds__(256) void stats_kernel(const unsigned short* __restrict__ in,
    float2* __restrict__ stats) {
  int token = blockIdx.x * 4 + (threadIdx.x >> 6);
  int lane = threadIdx.x & 63;
  const unsigned short* row = in + (size_t)token * CC;
  float s = 0.f, s2 = 0.f;
#pragma unroll
  for (int j = 0; j < 6; ++j) {
    float v = b2fl(row[lane + 64*j]);
    s += v; s2 += v*v;
  }
#pragma unroll
  for (int off = 32; off >= 1; off >>= 1) {
    s += __shfl_xor(s, off);
    s2 += __shfl_xor(s2, off);
  }
  if (lane == 0) {
    float mu = s * (1.0f/CC);
    float rs = rsqrtf(s2 * (1.0f/CC) - mu*mu + 1e-5f);
    stats[token] = make_float2(mu, rs);
  }
}

// ---------------- bf16 MFMA GEMM, BK=32 double-buffered 2-phase ----------------
// MODE 0: v = rs*acc - rs*mu*gs[n] + bb[n]; tanh-GELU; bf16 store (GEMM1)
// MODE 1: out = acc + xs(bf16) + x + b2, fp32 (GEMM2, residual fused)
template<int MODE>
__global__ __launch_bounds__(256) void mfma_gemm_kernel(
    const unsigned short* __restrict__ A, int lda,
    const unsigned short* __restrict__ BT, int ldbt,
    void* __restrict__ Cp, int ldc, int K, int ntn,
    const float2* __restrict__ stats, const float2* __restrict__ gsbb,
    const unsigned short* __restrict__ xsb, const float* __restrict__ xres,
    const float* __restrict__ b2v) {
  __shared__ __align__(16) char gsm[32768];  // 2 bufs x (A 8KB + B 8KB)
  int nb = (int)gridDim.x;
  int bidx = (int)blockIdx.x;
  int bswz = (bidx & 7) * (nb >> 3) + (bidx >> 3);
  int bn = bswz % ntn;
  int bm = bswz / ntn;
  int t = threadIdx.x;
  int lane = t & 63;
  int wid = t >> 6;
  int wm = wid >> 1, wn = wid & 1;
  int rr = lane & 15, rq = lane >> 4;

  f32x4 acc[4][4];
#pragma unroll
  for (int m = 0; m < 4; ++m)
#pragma unroll
    for (int n = 0; n < 4; ++n) acc[m][n] = (f32x4){0.f,0.f,0.f,0.f};

  const unsigned short* Abase = A + (size_t)bm*128*lda;
  const unsigned short* Bbase = BT + (size_t)bn*128*ldbt;
  int nt = K >> 5;

#define STG(bsel, t0)                                                        \
  {                                                                          \
    _Pragma("unroll")                                                        \
    for (int i = 0; i < 2; ++i) {                                            \
      int u = t + i*256;                                                     \
      int row = u >> 2, ch = u & 3;                                          \
      gload16(Abase + (size_t)row*lda + (t0)*32 + ((ch ^ (row & 3)) << 3),   \
              gsm + (bsel)*16384 + i*4096 + wid*1024);                       \
      gload16(Bbase + (size_t)row*ldbt + (t0)*32 + ((ch ^ (row & 3)) << 3),  \
              gsm + (bsel)*16384 + 8192 + i*4096 + wid*1024);                \
    }                                                                        \
  }

#define CMP(bsel)                                                            \
  {                                                                          \
    const char* Ab2 = gsm + (bsel)*16384;                                    \
    const char* Bb2 = Ab2 + 8192;                                            \
    bf16x8 af[4], bfv[4];                                                    \
    _Pragma("unroll")                                                        \
    for (int m = 0; m < 4; ++m) {                                            \
      int row = wm*64 + m*16 + rr;                                           \
      af[m] = *(const bf16x8*)(Ab2 + row*64 + ((rq ^ (row & 3)) << 4));      \
    }                                                                        \
    _Pragma("unroll")                                                        \
    for (int n = 0; n < 4; ++n) {                                            \
      int row = wn*64 + n*16 + rr;                                           \
      bfv[n] = *(const bf16x8*)(Bb2 + row*64 + ((rq ^ (row & 3)) << 4));     \
    }                                                                        \
    _Pragma("unroll")                                                        \
    for (int m = 0; m < 4; ++m)                                              \
      _Pragma("unroll")                                                      \
      for (int n = 0; n < 4; ++n)                                            \
        acc[m][n] = __builtin_amdgcn_mfma_f32_16x16x32_bf16(af[m], bfv[n], acc[m][n], 0, 0, 0); \
  }

  STG(0, 0);
  __syncthreads();
  int cur = 0;
  for (int tt = 0; tt < nt - 1; ++tt) {
    STG(cur ^ 1, tt + 1);
    CMP(cur);
    __syncthreads();
    cur ^= 1;
  }
  CMP(cur);
  __syncthreads();
#undef STG
#undef CMP

  if (MODE == 0) {
    unsigned short* ep = (unsigned short*)gsm;
#pragma unroll
    for (int m = 0; m < 4; ++m) {
      float2 st[4];
#pragma unroll
      for (int j = 0; j < 4; ++j)
        st[j] = stats[bm*128 + wm*64 + m*16 + rq*4 + j];
#pragma unroll
      for (int n = 0; n < 4; ++n) {
        int lcol = wn*64 + n*16 + rr;
        float2 gb = gsbb[bn*128 + lcol];
#pragma unroll
        for (int j = 0; j < 4; ++j) {
          float v = st[j].y * acc[m][n][j] - st[j].y * st[j].x * gb.x + gb.y;
          v = gelu_fast(v);
          int row = wm*64 + m*16 + rq*4 + j;
          ep[row*128 + (lcol ^ ((row & 7) << 3))] = f2b(v);
        }
      }
    }
    __syncthreads();
    for (int it = t; it < 128*16; it += 256) {
      int m = it >> 4, u8 = it & 15;
      uint4 pw = *(const uint4*)(ep + m*128 + ((u8*8) ^ ((m & 7) << 3)));
      *(uint4*)((unsigned short*)Cp + (size_t)(bm*128 + m)*ldc + bn*128 + u8*8) = pw;
    }
  } else {
    float* ep = (float*)gsm;
#pragma unroll
    for (int half = 0; half < 2; ++half) {
      __syncthreads();
#pragma unroll
      for (int mo = 0; mo < 2; ++mo) {
        int m = half*2 + mo;
#pragma unroll
        for (int n = 0; n < 4; ++n)
#pragma unroll
          for (int j = 0; j < 4; ++j) {
            int lr = wm*32 + mo*16 + rq*4 + j;
            int col = wn*64 + n*16 + rr;
            ep[lr*128 + (col ^ ((lr & 7) << 2))] = acc[m][n][j];
          }
      }
      __syncthreads();
      for (int it = t; it < 64*32; it += 256) {
        int lr = it >> 5, u = it & 31;
        int swz = (lr & 7) << 2;
        float4 v = *(const float4*)(ep + lr*128 + ((u*4) ^ swz));
        int grow = bm*128 + (lr >> 5)*64 + (half*2 + ((lr >> 4) & 1))*16 + (lr & 15);
        int gcol = bn*128 + u*4;
        size_t idx = (size_t)grow*ldc + gcol;
        float4 xr = *(const float4*)(xres + idx);
        uint2 xsv = *(const uint2*)(xsb + idx);
        float4 bv = *(const float4*)(b2v + gcol);
        float4 ov;
        ov.x = v.x + xr.x + b2fl((unsigned short)(xsv.x & 0xffffu)) + bv.x;
        ov.y = v.y + xr.y + b2fl((unsigned short)(xsv.x >> 16)) + bv.y;
        ov.z = v.z + xr.z + b2fl((unsigned short)(xsv.y & 0xffffu)) + bv.z;
        ov.w = v.w + xr.w + b2fl((unsigned short)(xsv.y >> 16)) + bv.w;
        *(float4*)((float*)Cp + idx) = ov;
      }
    }
  }
}

extern "C" void kernel_launch(void* const* d_in, const int* in_sizes, int n_in,
                              void* d_out, int out_size, void* d_ws, size_t ws_size,
                              hipStream_t stream) {
  const float* x   = (const float*)d_in[0];
  const float* w1  = (const float*)d_in[1];
  const float* b1  = (const float*)d_in[2];
  const float* n1w = (const float*)d_in[3];
  const float* n1b = (const float*)d_in[4];
  const float* n2w = (const float*)d_in[5];
  const float* n2b = (const float*)d_in[6];
  const float* mw1 = (const float*)d_in[7];
  const float* mb1 = (const float*)d_in[8];
  const float* mw2 = (const float*)d_in[9];
  const float* mb2 = (const float*)d_in[10];
  float* out = (float*)d_out;

  char* ws = (char*)d_ws;
  const size_t MB = 1ull << 20;
  unsigned short* xn  = (unsigned short*)(ws + 0*MB);    // 25.2 MB [b,h,c,w]
  unsigned short* S1  = (unsigned short*)(ws + 26*MB);   // 26 [b,h,m66,c]
  unsigned short* S2  = (unsigned short*)(ws + 53*MB);   // 26 [b2cp,kh,kw,c]
  unsigned short* o1  = (unsigned short*)(ws + 80*MB);   // 26 [b2cp,kw,h,c]
  unsigned short* S3  = (unsigned short*)(ws + 107*MB);  // 25.2 [b,kp,h,c]
  unsigned short* xsb = (unsigned short*)(ws + 133*MB);  // 25.2 bf16 xs
  float2*         stats = (float2*)(ws + 159*MB);        // 256 KB (mu, rs)
  unsigned short* hid = (unsigned short*)(ws + 160*MB);  // 100.7 bf16
  unsigned short* w1t = (unsigned short*)(ws + 261*MB);  // 1.2 bf16 (g-folded)
  unsigned short* w2t = (unsigned short*)(ws + 263*MB);  // 1.2 bf16
  unsigned short* atab = (unsigned short*)(ws + 265*MB);
  float2*         gsbb = (float2*)(ws + 266*MB);

  // merged LN1 (blocks 0..511) + prep (blocks 512..1733)
  prep_ln1_kernel<<<1734, 256, 0, stream>>>(x, n1w, n1b, xn,
                                            atab, mw1, w1t, mw2, w2t,
                                            n2w, n2b, mb1, gsbb);
  // W-fwd
  dft_kernel<0><<<512*3, 256, 0, stream>>>(atab, xn, S1);
  // H-fwd
  dft_kernel<1><<<264*3, 256, 0, stream>>>(atab, S1, S2);
  // block-diag complex matmul + ReLU
  blockmm2_kernel<<<64*WF*4, 384, 0, stream>>>(S2, w1, b1, o1);
  // H-inv
  dft_kernel<2><<<264*3, 256, 0, stream>>>(atab, o1, S3);
  // W-inv -> xs (bf16)
  dft_kernel<3><<<512*3, 256, 0, stream>>>(atab, S3, xsb);
  // LN2 stats
  stats_kernel<<<NTOK/4, 256, 0, stream>>>(xsb, stats);
  // GEMM1: hid = gelu(LN2(xs) @ W1 + b1)  M=32768 N=1536 K=384
  mfma_gemm_kernel<0><<<256*12, 256, 0, stream>>>(xsb, 384, w1t, 384,
                                                  hid, 1536, 384, 12,
                                                  stats, gsbb, nullptr, nullptr, nullptr);
  // GEMM2: out = hid @ W2 + xs + x + b2  M=32768 N=384 K=1536
  mfma_gemm_kernel<1><<<256*3, 256, 0, stream>>>(hid, 1536, w2t, 1536,
                                                 out, 384, 1536, 3,
                                                 nullptr, nullptr, xsb, x, mb2);
}